// Round 1
// baseline (4060.285 us; speedup 1.0000x reference)
//
#include <hip/hip_runtime.h>
#include <hip/hip_bf16.h>

// Problem constants (guarded against in_sizes at launch):
//   N_NODES=50000, N_EDGES=1600000, ATOM_F=64, FP_SIZE=2048, N_GRAPHS=2000
#define AF 64
#define NFP 2048

// ---------------------------------------------------------------------------
// Kernel 1: edge scatter-add  agg[dst] += h[src]
// thread per (edge, float4-chunk): 16 threads per edge
// ---------------------------------------------------------------------------
__global__ __launch_bounds__(256) void scatter_add_kernel(
    const float* __restrict__ h, const int* __restrict__ src,
    const int* __restrict__ dst, float* __restrict__ agg, int n_edges)
{
    long long idx = (long long)blockIdx.x * 256 + threadIdx.x;
    long long total = (long long)n_edges * 16;
    if (idx >= total) return;
    int e  = (int)(idx >> 4);
    int f4 = (int)(idx & 15);
    int sv = src[e];
    int dv = dst[e];
    const float4 v = *reinterpret_cast<const float4*>(&h[(size_t)sv * AF + f4 * 4]);
    float* p = &agg[(size_t)dv * AF + f4 * 4];
    unsafeAtomicAdd(p + 0, v.x);
    unsafeAtomicAdd(p + 1, v.y);
    unsafeAtomicAdd(p + 2, v.z);
    unsafeAtomicAdd(p + 3, v.w);
}

// ---------------------------------------------------------------------------
// Kernel 2: node MLP  out[i] = sigmoid((agg[i] + hx[i]) @ Hw^T + Hb)
// 4 nodes per block (1 per wave). Hw staged in LDS with +1 padding
// (row j at HwT[j*65+k]): compute-read bank = (j+k)%32 -> conflict-free.
// Safe to run in place (out == agg): row read fully before write.
// ---------------------------------------------------------------------------
__global__ __launch_bounds__(256) void node_mlp_kernel(
    const float* __restrict__ agg, const float* __restrict__ hx,
    const float* __restrict__ Hw, const float* __restrict__ Hb,
    float* __restrict__ out, int n_nodes)
{
    __shared__ float Hw_s[AF * 65];
    __shared__ float a_s[4][AF];
    __shared__ float hb_s[AF];

    int t = threadIdx.x;
    for (int idx = t; idx < AF * AF; idx += 256) {
        int j = idx >> 6, k = idx & 63;
        Hw_s[j * 65 + k] = Hw[idx];
    }
    if (t < AF) hb_s[t] = Hb[t];

    int w = t >> 6, lane = t & 63;
    int i = blockIdx.x * 4 + w;
    if (i < n_nodes)
        a_s[w][lane] = agg[(size_t)i * AF + lane] + hx[(size_t)i * AF + lane];
    __syncthreads();

    if (i < n_nodes) {
        float acc = 0.f;
        #pragma unroll
        for (int k = 0; k < AF; ++k)
            acc = fmaf(a_s[w][k], Hw_s[lane * 65 + k], acc);
        acc += hb_s[lane];
        out[(size_t)i * AF + lane] = 1.f / (1.f + __expf(-acc));
    }
}

// ---------------------------------------------------------------------------
// Kernel 3: fingerprint + softmax + graph pooling, fused.
// Block = 256 threads handles 8 nodes. Thread t owns j = r*256+t (r=0..7);
// z kept entirely in registers (acc[8][8] = [r][node]).
// Ww streamed from L2 once per block. Softmax via shuffle + 4-slot LDS.
// Pool into LDS facc[2048], flushed with atomics once per graph-run
// (batch is sorted, so ~1-2 flushes per block).
// ---------------------------------------------------------------------------
__global__ __launch_bounds__(256) void fp_pool_kernel(
    const float* __restrict__ upd, const float* __restrict__ Ww,
    const float* __restrict__ Wb, const int* __restrict__ batch,
    float* __restrict__ out, int n_nodes)
{
    __shared__ float upd_s[8][AF];
    __shared__ float facc[NFP];
    __shared__ float wred[4];

    int t = threadIdx.x;
    int wave = t >> 6, lane = t & 63;
    int i0 = blockIdx.x * 8;
    int nvalid = n_nodes - i0;
    if (nvalid > 8) nvalid = 8;
    if (nvalid <= 0) return;

    for (int idx = t; idx < 8 * AF; idx += 256) {
        int n = idx >> 6, k = idx & 63;
        upd_s[n][k] = (n < nvalid) ? upd[(size_t)(i0 + n) * AF + k] : 0.f;
    }
    #pragma unroll
    for (int r = 0; r < 8; ++r) facc[r * 256 + t] = 0.f;
    __syncthreads();

    float acc[8][8];
    #pragma unroll
    for (int r = 0; r < 8; ++r)
        #pragma unroll
        for (int n = 0; n < 8; ++n) acc[r][n] = 0.f;

    #pragma unroll 2
    for (int k4 = 0; k4 < 16; ++k4) {
        float4 w4[8];
        #pragma unroll
        for (int r = 0; r < 8; ++r)
            w4[r] = *reinterpret_cast<const float4*>(
                &Ww[(size_t)(r * 256 + t) * AF + k4 * 4]);
        #pragma unroll
        for (int n = 0; n < 8; ++n) {
            float4 u4 = *reinterpret_cast<const float4*>(&upd_s[n][k4 * 4]);
            #pragma unroll
            for (int r = 0; r < 8; ++r)
                acc[r][n] = fmaf(u4.w, w4[r].w,
                            fmaf(u4.z, w4[r].z,
                            fmaf(u4.y, w4[r].y,
                            fmaf(u4.x, w4[r].x, acc[r][n]))));
        }
    }
    #pragma unroll
    for (int r = 0; r < 8; ++r) {
        float bb = Wb[r * 256 + t];
        #pragma unroll
        for (int n = 0; n < 8; ++n) acc[r][n] += bb;
    }

    int gprev = -1;
    for (int n = 0; n < nvalid; ++n) {
        // --- block-wide max over 2048 ---
        float m = acc[0][n];
        #pragma unroll
        for (int r = 1; r < 8; ++r) m = fmaxf(m, acc[r][n]);
        #pragma unroll
        for (int off = 32; off >= 1; off >>= 1) m = fmaxf(m, __shfl_xor(m, off));
        if (lane == 0) wred[wave] = m;
        __syncthreads();
        m = fmaxf(fmaxf(wred[0], wred[1]), fmaxf(wred[2], wred[3]));
        __syncthreads();
        // --- exp + block-wide sum ---
        float e[8];
        float s = 0.f;
        #pragma unroll
        for (int r = 0; r < 8; ++r) { e[r] = __expf(acc[r][n] - m); s += e[r]; }
        #pragma unroll
        for (int off = 32; off >= 1; off >>= 1) s += __shfl_xor(s, off);
        if (lane == 0) wred[wave] = s;
        __syncthreads();
        s = wred[0] + wred[1] + wred[2] + wred[3];
        float inv = 1.f / s;

        int g = batch[i0 + n];  // uniform across block
        if (g != gprev) {
            if (gprev >= 0) {
                #pragma unroll
                for (int r = 0; r < 8; ++r) {
                    int j = r * 256 + t;
                    unsafeAtomicAdd(&out[(size_t)gprev * NFP + j], facc[j]);
                    facc[j] = 0.f;   // thread-exclusive j: no barrier needed
                }
            }
            gprev = g;
        }
        #pragma unroll
        for (int r = 0; r < 8; ++r) facc[r * 256 + t] += e[r] * inv;
        __syncthreads();  // protect wred before next iteration's writes
    }
    if (gprev >= 0) {
        #pragma unroll
        for (int r = 0; r < 8; ++r) {
            int j = r * 256 + t;
            unsafeAtomicAdd(&out[(size_t)gprev * NFP + j], facc[j]);
        }
    }
}

// ---------------------------------------------------------------------------
extern "C" void kernel_launch(void* const* d_in, const int* in_sizes, int n_in,
                              void* d_out, int out_size, void* d_ws, size_t ws_size,
                              hipStream_t stream)
{
    const float* x    = (const float*)d_in[0];
    const float* H1_w = (const float*)d_in[1];
    const float* H1_b = (const float*)d_in[2];
    const float* W1_w = (const float*)d_in[3];
    const float* W1_b = (const float*)d_in[4];
    const float* H2_w = (const float*)d_in[5];
    const float* H2_b = (const float*)d_in[6];
    const float* W2_w = (const float*)d_in[7];
    const float* W2_b = (const float*)d_in[8];
    const int*   ei   = (const int*)d_in[9];
    const int*   batch= (const int*)d_in[10];

    const int n_nodes = in_sizes[0] / AF;   // 50000
    const int n_edges = in_sizes[9] / 2;    // 1600000
    const int* src = ei;
    const int* dst = ei + n_edges;
    float* out = (float*)d_out;

    float* bufA = (float*)d_ws;                       // agg (both layers), upd2
    float* bufB = bufA + (size_t)n_nodes * AF;        // upd1
    const size_t node_bytes = (size_t)n_nodes * AF * sizeof(float);

    const int sc_blocks  = (int)(((long long)n_edges * 16 + 255) / 256);
    const int mlp_blocks = (n_nodes + 3) / 4;
    const int fp_blocks  = (n_nodes + 7) / 8;

    // ---- layer 1 ----
    hipMemsetAsync(bufA, 0, node_bytes, stream);
    hipMemsetAsync(d_out, 0, (size_t)out_size * sizeof(float), stream);
    scatter_add_kernel<<<sc_blocks, 256, 0, stream>>>(x, src, dst, bufA, n_edges);
    node_mlp_kernel<<<mlp_blocks, 256, 0, stream>>>(bufA, x, H1_w, H1_b, bufB, n_nodes);
    fp_pool_kernel<<<fp_blocks, 256, 0, stream>>>(bufB, W1_w, W1_b, batch, out, n_nodes);

    // ---- layer 2 ----
    hipMemsetAsync(bufA, 0, node_bytes, stream);
    scatter_add_kernel<<<sc_blocks, 256, 0, stream>>>(bufB, src, dst, bufA, n_edges);
    node_mlp_kernel<<<mlp_blocks, 256, 0, stream>>>(bufA, bufB, H2_w, H2_b, bufA, n_nodes);
    fp_pool_kernel<<<fp_blocks, 256, 0, stream>>>(bufA, W2_w, W2_b, batch, out, n_nodes);
}

// Round 2
// 1435.493 us; speedup vs baseline: 2.8285x; 2.8285x over previous
//
#include <hip/hip_runtime.h>
#include <hip/hip_bf16.h>

// N_NODES=50000, N_EDGES=1600000, ATOM_F=64, FP_SIZE=2048, N_GRAPHS=2000
#define AF 64
#define NFP 2048

// ---------------------------------------------------------------------------
// CSR build: histogram of dst, exclusive scan, scatter src-ids.
// Built ONCE per launch, reused by both layers (edges don't change).
// ---------------------------------------------------------------------------
__global__ __launch_bounds__(256) void hist_kernel(
    const int* __restrict__ dst, int* __restrict__ counts, int n_edges)
{
    int e = blockIdx.x * 256 + threadIdx.x;
    if (e < n_edges) atomicAdd(&counts[dst[e]], 1);
}

// single-block exclusive scan, in place; data[n] = total
__global__ __launch_bounds__(1024) void scan_kernel(int* data, int n)
{
    __shared__ int wsum[16];
    __shared__ int chunk_total;
    int t = threadIdx.x, lane = t & 63, w = t >> 6;
    int running = 0;
    for (int base = 0; base < n; base += 1024) {
        int i = base + t;
        int v = (i < n) ? data[i] : 0;
        int x = v;
        #pragma unroll
        for (int off = 1; off < 64; off <<= 1) {
            int y = __shfl_up(x, off);
            if (lane >= off) x += y;
        }
        if (lane == 63) wsum[w] = x;
        __syncthreads();
        if (t == 0) {
            int s = 0;
            #pragma unroll
            for (int q = 0; q < 16; ++q) { int tmp = wsum[q]; wsum[q] = s; s += tmp; }
            chunk_total = s;
        }
        __syncthreads();
        if (i < n) data[i] = x - v + wsum[w] + running;
        running += chunk_total;
        __syncthreads();
    }
    if (t == 0) data[n] = running;
}

__global__ __launch_bounds__(256) void scatter_ids_kernel(
    const int* __restrict__ src, const int* __restrict__ dst,
    int* __restrict__ cursor, int* __restrict__ esrc, int n_edges)
{
    int e = blockIdx.x * 256 + threadIdx.x;
    if (e < n_edges) {
        int pos = atomicAdd(&cursor[dst[e]], 1);
        esrc[pos] = src[e];
    }
}

// ---------------------------------------------------------------------------
// Transpose Ww [2048][64] -> WwT [64][2048] so fp_pool's weight loads coalesce.
// ---------------------------------------------------------------------------
__global__ __launch_bounds__(256) void transpose64_kernel(
    const float* __restrict__ W, float* __restrict__ WT)
{
    __shared__ float tile[64][65];
    int j0 = blockIdx.x * 64;
    int t = threadIdx.x;
    for (int idx = t; idx < 4096; idx += 256) {
        int r = idx >> 6, k = idx & 63;
        tile[r][k] = W[(size_t)(j0 + r) * AF + k];
    }
    __syncthreads();
    for (int idx = t; idx < 4096; idx += 256) {
        int k = idx >> 6, r = idx & 63;
        WT[(size_t)k * NFP + j0 + r] = tile[r][k];
    }
}

// ---------------------------------------------------------------------------
// Fused gather-aggregate (CSR, no atomics) + self-loop + 64x64 sigmoid MLP.
// Block=256: 4 nodes (1/wave). Within a wave: 4 edges processed at once
// (16 lanes x float4 per edge). Hw staged in LDS, +1 pad, conflict-free.
// ---------------------------------------------------------------------------
__global__ __launch_bounds__(256) void agg_mlp_kernel(
    const float* __restrict__ h, const int* __restrict__ offsets,
    const int* __restrict__ esrc, const float* __restrict__ Hw,
    const float* __restrict__ Hb, float* __restrict__ out, int n_nodes)
{
    __shared__ float Hw_s[AF * 65];
    __shared__ __align__(16) float part[4][4][AF];  // [wave][sub][feat]
    __shared__ float a_red[4][AF];
    __shared__ float hb_s[AF];

    int t = threadIdx.x;
    for (int idx = t; idx < AF * AF; idx += 256) {
        int j = idx >> 6, k = idx & 63;
        Hw_s[j * 65 + k] = Hw[idx];
    }
    if (t < AF) hb_s[t] = Hb[t];

    int w = t >> 6, lane = t & 63;
    int sub = lane >> 4, f4 = lane & 15;
    int i = blockIdx.x * 4 + w;

    float4 acc = make_float4(0.f, 0.f, 0.f, 0.f);
    if (i < n_nodes) {
        int o0 = offsets[i], o1 = offsets[i + 1];
        const int* ep = esrc + o0;
        int deg = o1 - o0;
        const float4* h4 = (const float4*)h;
        int j = 0;
        for (; j + 4 <= deg; j += 4) {
            int s = ep[j + sub];
            float4 v = h4[(size_t)s * 16 + f4];
            acc.x += v.x; acc.y += v.y; acc.z += v.z; acc.w += v.w;
        }
        if (j + sub < deg) {
            int s = ep[j + sub];
            float4 v = h4[(size_t)s * 16 + f4];
            acc.x += v.x; acc.y += v.y; acc.z += v.z; acc.w += v.w;
        }
    }
    *(float4*)&part[w][sub][f4 * 4] = acc;
    __syncthreads();

    if (i < n_nodes) {
        float val = h[(size_t)i * AF + lane]      // self loop
                  + part[w][0][lane] + part[w][1][lane]
                  + part[w][2][lane] + part[w][3][lane];
        a_red[w][lane] = val;
    }
    __syncthreads();

    if (i < n_nodes) {
        float z = hb_s[lane];
        #pragma unroll
        for (int k = 0; k < AF; ++k)
            z = fmaf(a_red[w][k], Hw_s[lane * 65 + k], z);
        out[(size_t)i * AF + lane] = 1.f / (1.f + __expf(-z));
    }
}

// ---------------------------------------------------------------------------
// Fingerprint GEMM (coalesced via WwT) + softmax + pooled atomically-flushed
// LDS accumulator. Block=256 handles 8 nodes; thread t owns j = t*4..t*4+3
// (group A) and 1024 + t*4.. (group B): 64 acc regs, all in registers.
// ---------------------------------------------------------------------------
__global__ __launch_bounds__(256) void fp_pool_kernel(
    const float* __restrict__ upd, const float* __restrict__ WwT,
    const float* __restrict__ Wb, const int* __restrict__ batch,
    float* __restrict__ out, int n_nodes)
{
    __shared__ __align__(16) float upd_s[8][AF];
    __shared__ __align__(16) float facc[NFP];
    __shared__ float wred[4];

    int t = threadIdx.x, wave = t >> 6, lane = t & 63;
    int i0 = blockIdx.x * 8;
    int nvalid = n_nodes - i0;
    if (nvalid > 8) nvalid = 8;
    if (nvalid <= 0) return;

    for (int idx = t; idx < 128; idx += 256) {
        int n = idx >> 4, q = idx & 15;
        float4 v = make_float4(0.f, 0.f, 0.f, 0.f);
        if (n < nvalid) v = *(const float4*)&upd[(size_t)(i0 + n) * AF + q * 4];
        *(float4*)&upd_s[n][q * 4] = v;
    }
    #pragma unroll
    for (int r = 0; r < 8; ++r) facc[r * 256 + t] = 0.f;
    __syncthreads();

    float4 accA[8], accB[8];
    #pragma unroll
    for (int n = 0; n < 8; ++n) {
        accA[n] = make_float4(0.f, 0.f, 0.f, 0.f);
        accB[n] = make_float4(0.f, 0.f, 0.f, 0.f);
    }

    #pragma unroll 2
    for (int k4 = 0; k4 < 16; ++k4) {
        float4 u4[8];
        #pragma unroll
        for (int n = 0; n < 8; ++n) u4[n] = *(const float4*)&upd_s[n][k4 * 4];
        #pragma unroll
        for (int c = 0; c < 4; ++c) {
            int k = k4 * 4 + c;
            float4 wa = *(const float4*)&WwT[(size_t)k * NFP + t * 4];
            float4 wb = *(const float4*)&WwT[(size_t)k * NFP + 1024 + t * 4];
            #pragma unroll
            for (int n = 0; n < 8; ++n) {
                float u = (c == 0) ? u4[n].x : (c == 1) ? u4[n].y
                        : (c == 2) ? u4[n].z : u4[n].w;
                accA[n].x = fmaf(u, wa.x, accA[n].x);
                accA[n].y = fmaf(u, wa.y, accA[n].y);
                accA[n].z = fmaf(u, wa.z, accA[n].z);
                accA[n].w = fmaf(u, wa.w, accA[n].w);
                accB[n].x = fmaf(u, wb.x, accB[n].x);
                accB[n].y = fmaf(u, wb.y, accB[n].y);
                accB[n].z = fmaf(u, wb.z, accB[n].z);
                accB[n].w = fmaf(u, wb.w, accB[n].w);
            }
        }
    }
    {
        float4 ba = *(const float4*)&Wb[t * 4];
        float4 bb = *(const float4*)&Wb[1024 + t * 4];
        #pragma unroll
        for (int n = 0; n < 8; ++n) {
            accA[n].x += ba.x; accA[n].y += ba.y; accA[n].z += ba.z; accA[n].w += ba.w;
            accB[n].x += bb.x; accB[n].y += bb.y; accB[n].z += bb.z; accB[n].w += bb.w;
        }
    }

    int gprev = -1;
    for (int n = 0; n < nvalid; ++n) {
        float m = fmaxf(fmaxf(fmaxf(accA[n].x, accA[n].y), fmaxf(accA[n].z, accA[n].w)),
                        fmaxf(fmaxf(accB[n].x, accB[n].y), fmaxf(accB[n].z, accB[n].w)));
        #pragma unroll
        for (int off = 32; off >= 1; off >>= 1) m = fmaxf(m, __shfl_xor(m, off));
        if (lane == 0) wred[wave] = m;
        __syncthreads();
        m = fmaxf(fmaxf(wred[0], wred[1]), fmaxf(wred[2], wred[3]));
        __syncthreads();

        float4 ea, eb;
        ea.x = __expf(accA[n].x - m); ea.y = __expf(accA[n].y - m);
        ea.z = __expf(accA[n].z - m); ea.w = __expf(accA[n].w - m);
        eb.x = __expf(accB[n].x - m); eb.y = __expf(accB[n].y - m);
        eb.z = __expf(accB[n].z - m); eb.w = __expf(accB[n].w - m);
        float s = ea.x + ea.y + ea.z + ea.w + eb.x + eb.y + eb.z + eb.w;
        #pragma unroll
        for (int off = 32; off >= 1; off >>= 1) s += __shfl_xor(s, off);
        if (lane == 0) wred[wave] = s;
        __syncthreads();
        s = wred[0] + wred[1] + wred[2] + wred[3];
        float inv = 1.f / s;

        int g = batch[i0 + n];  // block-uniform (nodes sorted by graph)
        if (g != gprev) {
            if (gprev >= 0) {
                float4 fa = *(float4*)&facc[t * 4];
                float4 fb = *(float4*)&facc[1024 + t * 4];
                float* po = &out[(size_t)gprev * NFP];
                unsafeAtomicAdd(po + t * 4 + 0, fa.x);
                unsafeAtomicAdd(po + t * 4 + 1, fa.y);
                unsafeAtomicAdd(po + t * 4 + 2, fa.z);
                unsafeAtomicAdd(po + t * 4 + 3, fa.w);
                unsafeAtomicAdd(po + 1024 + t * 4 + 0, fb.x);
                unsafeAtomicAdd(po + 1024 + t * 4 + 1, fb.y);
                unsafeAtomicAdd(po + 1024 + t * 4 + 2, fb.z);
                unsafeAtomicAdd(po + 1024 + t * 4 + 3, fb.w);
                float4 z4 = make_float4(0.f, 0.f, 0.f, 0.f);
                *(float4*)&facc[t * 4] = z4;            // thread-exclusive slots
                *(float4*)&facc[1024 + t * 4] = z4;
            }
            gprev = g;
        }
        {
            float4 fa = *(float4*)&facc[t * 4];
            fa.x += ea.x * inv; fa.y += ea.y * inv; fa.z += ea.z * inv; fa.w += ea.w * inv;
            *(float4*)&facc[t * 4] = fa;
            float4 fb = *(float4*)&facc[1024 + t * 4];
            fb.x += eb.x * inv; fb.y += eb.y * inv; fb.z += eb.z * inv; fb.w += eb.w * inv;
            *(float4*)&facc[1024 + t * 4] = fb;
        }
        __syncthreads();  // protect wred before next iteration
    }
    if (gprev >= 0) {
        float4 fa = *(float4*)&facc[t * 4];
        float4 fb = *(float4*)&facc[1024 + t * 4];
        float* po = &out[(size_t)gprev * NFP];
        unsafeAtomicAdd(po + t * 4 + 0, fa.x);
        unsafeAtomicAdd(po + t * 4 + 1, fa.y);
        unsafeAtomicAdd(po + t * 4 + 2, fa.z);
        unsafeAtomicAdd(po + t * 4 + 3, fa.w);
        unsafeAtomicAdd(po + 1024 + t * 4 + 0, fb.x);
        unsafeAtomicAdd(po + 1024 + t * 4 + 1, fb.y);
        unsafeAtomicAdd(po + 1024 + t * 4 + 2, fb.z);
        unsafeAtomicAdd(po + 1024 + t * 4 + 3, fb.w);
    }
}

// ---------------------------------------------------------------------------
extern "C" void kernel_launch(void* const* d_in, const int* in_sizes, int n_in,
                              void* d_out, int out_size, void* d_ws, size_t ws_size,
                              hipStream_t stream)
{
    const float* x    = (const float*)d_in[0];
    const float* H1_w = (const float*)d_in[1];
    const float* H1_b = (const float*)d_in[2];
    const float* W1_w = (const float*)d_in[3];
    const float* W1_b = (const float*)d_in[4];
    const float* H2_w = (const float*)d_in[5];
    const float* H2_b = (const float*)d_in[6];
    const float* W2_w = (const float*)d_in[7];
    const float* W2_b = (const float*)d_in[8];
    const int*   ei   = (const int*)d_in[9];
    const int*   batch= (const int*)d_in[10];

    const int n_nodes = in_sizes[0] / AF;   // 50000
    const int n_edges = in_sizes[9] / 2;    // 1600000
    const int* src = ei;
    const int* dst = ei + n_edges;
    float* out = (float*)d_out;

    // workspace layout
    float* bufA    = (float*)d_ws;                          // 3.2M floats
    float* bufB    = bufA + (size_t)n_nodes * AF;           // 3.2M floats
    float* WwT1    = bufB + (size_t)n_nodes * AF;           // 131072
    float* WwT2    = WwT1 + (size_t)AF * NFP;               // 131072
    int*   offsets = (int*)(WwT2 + (size_t)AF * NFP);       // n_nodes+1
    int*   cursor  = offsets + (n_nodes + 1);               // n_nodes+1
    int*   esrc    = cursor + (n_nodes + 1);                // n_edges

    const int eb = (n_edges + 255) / 256;
    const int mlp_blocks = (n_nodes + 3) / 4;
    const int fp_blocks  = (n_nodes + 7) / 8;

    // --- one-time per launch: weight transposes + CSR build ---
    transpose64_kernel<<<NFP / 64, 256, 0, stream>>>(W1_w, WwT1);
    transpose64_kernel<<<NFP / 64, 256, 0, stream>>>(W2_w, WwT2);
    hipMemsetAsync(offsets, 0, (size_t)(n_nodes + 1) * sizeof(int), stream);
    hist_kernel<<<eb, 256, 0, stream>>>(dst, offsets, n_edges);
    scan_kernel<<<1, 1024, 0, stream>>>(offsets, n_nodes);
    hipMemcpyAsync(cursor, offsets, (size_t)n_nodes * sizeof(int),
                   hipMemcpyDeviceToDevice, stream);
    scatter_ids_kernel<<<eb, 256, 0, stream>>>(src, dst, cursor, esrc, n_edges);
    hipMemsetAsync(d_out, 0, (size_t)out_size * sizeof(float), stream);

    // --- layer 1 ---
    agg_mlp_kernel<<<mlp_blocks, 256, 0, stream>>>(x, offsets, esrc, H1_w, H1_b, bufB, n_nodes);
    fp_pool_kernel<<<fp_blocks, 256, 0, stream>>>(bufB, WwT1, W1_b, batch, out, n_nodes);

    // --- layer 2 ---
    agg_mlp_kernel<<<mlp_blocks, 256, 0, stream>>>(bufB, offsets, esrc, H2_w, H2_b, bufA, n_nodes);
    fp_pool_kernel<<<fp_blocks, 256, 0, stream>>>(bufA, WwT2, W2_b, batch, out, n_nodes);
}